// Round 1
// baseline (160.623 us; speedup 1.0000x reference)
//
#include <hip/hip_runtime.h>

#define BATCH 16384
#define LATENT 128
#define HIDDEN 64
#define INDIM 100
#define KPAD 128

typedef short shortx8 __attribute__((ext_vector_type(8)));
typedef float floatx4 __attribute__((ext_vector_type(4)));

__device__ __forceinline__ short f2bf(float f) {
    union { float f; unsigned u; } v; v.f = f;
    unsigned r = v.u + 0x7FFF + ((v.u >> 16) & 1);   // RNE, inputs finite
    return (short)(r >> 16);
}

__device__ __forceinline__ float tanh_fast(float x) {
    float e = __expf(2.0f * x);
    return 1.0f - 2.0f / (e + 1.0f);
}

// --- pre-pass: u[16384][100] fp32 -> fragment-major bf16, b1 folded via k=100 col of ones ---
// uf chunk index c = ((g*4 + kt)*64 + lane); value j: A[row=g*16+(lane&15)][k=kt*32+(lane>>4)*8+j]
__global__ __launch_bounds__(256) void prep_u(const float* __restrict__ u, shortx8* __restrict__ uf) {
    int c = blockIdx.x * 256 + threadIdx.x;          // 0 .. 262143
    int lane = c & 63;
    int kt = (c >> 6) & 3;
    int g = c >> 8;
    int row = g * 16 + (lane & 15);
    int kbase = kt * 32 + ((lane >> 4) << 3);
    shortx8 v;
#pragma unroll
    for (int j = 0; j < 8; j++) {
        int k = kbase + j;
        float f = (k < INDIM) ? u[row * INDIM + k] : (k == INDIM ? 1.0f : 0.0f);
        v[j] = f2bf(f);
    }
    uf[c] = v;
}

// --- pre-pass: W1[128][64][100] fp32 -> fragment-major bf16 (B^T layout), b1 in k=100 ---
// wf chunk index c = (((lat*4+nt)*4+kt)*64+lane); value j: B^T[h=nt*16+(lane&15)][k=kt*32+(lane>>4)*8+j]
__global__ __launch_bounds__(256) void prep_w(const float* __restrict__ W1, const float* __restrict__ b1,
                                              shortx8* __restrict__ wf) {
    int c = blockIdx.x * 256 + threadIdx.x;          // 0 .. 131071
    int lane = c & 63;
    int kt = (c >> 6) & 3;
    int nt = (c >> 8) & 3;
    int lat = c >> 10;
    int h = nt * 16 + (lane & 15);
    int hw = lat * HIDDEN + h;
    int kbase = kt * 32 + ((lane >> 4) << 3);
    shortx8 v;
#pragma unroll
    for (int j = 0; j < 8; j++) {
        int k = kbase + j;
        float f = (k < INDIM) ? W1[hw * INDIM + k] : (k == INDIM ? b1[hw] : 0.0f);
        v[j] = f2bf(f);
    }
    wf[c] = v;
}

// --- main fused kernel ---
// grid (128, 32): bx = 128-row batch block, by = 4-latent quad. 256 thr = 4 waves.
// wave w: row-groups g0=bx*8+w*2, g0+1 (16 rows each). All 4 latents of the quad.
__global__ __launch_bounds__(256) void branch_mlp(const shortx8* __restrict__ uf,
                                                  const shortx8* __restrict__ wf,
                                                  const float* __restrict__ W2,
                                                  const float* __restrict__ b2,
                                                  float* __restrict__ out) {
    int tid = threadIdx.x;
    int lane = tid & 63;
    int w = tid >> 6;
    int bx = blockIdx.x;
    int by = blockIdx.y;
    int g0 = bx * 8 + w * 2;
    int q = lane >> 4;
    int col = lane & 15;

    // A fragments for this wave's 32 rows, all K (registers, reused across 4 latents)
    shortx8 a[2][4];
#pragma unroll
    for (int gi = 0; gi < 2; gi++)
#pragma unroll
        for (int kt = 0; kt < 4; kt++)
            a[gi][kt] = uf[((g0 + gi) * 4 + kt) * 64 + lane];

#pragma unroll
    for (int li = 0; li < 4; li++) {
        int lat = by * 4 + li;
        floatx4 acc[2][4] = {};
#pragma unroll
        for (int kt = 0; kt < 4; kt++) {
#pragma unroll
            for (int nt = 0; nt < 4; nt++) {
                shortx8 bf = wf[((lat * 4 + nt) * 4 + kt) * 64 + lane];
#pragma unroll
                for (int gi = 0; gi < 2; gi++)
                    acc[gi][nt] = __builtin_amdgcn_mfma_f32_16x16x32_bf16(a[gi][kt], bf, acc[gi][nt], 0, 0, 0);
            }
        }
        // epilogue: tanh, scale by W2, reduce over hidden (cols), add b2
        float w2v[4];
#pragma unroll
        for (int nt = 0; nt < 4; nt++) w2v[nt] = W2[lat * HIDDEN + nt * 16 + col];
        float b2v = b2[lat];
#pragma unroll
        for (int gi = 0; gi < 2; gi++) {
            float p[4];
#pragma unroll
            for (int r = 0; r < 4; r++) {
                float s = 0.0f;
#pragma unroll
                for (int nt = 0; nt < 4; nt++)
                    s += tanh_fast(acc[gi][nt][r]) * w2v[nt];
                p[r] = s;
            }
#pragma unroll
            for (int r = 0; r < 4; r++) {
#pragma unroll
                for (int off = 1; off < 16; off <<= 1)
                    p[r] += __shfl_xor(p[r], off, 64);
            }
            if (col == 0) {
                int rowbase = (g0 + gi) * 16 + q * 4;
#pragma unroll
                for (int r = 0; r < 4; r++)
                    out[(rowbase + r) * LATENT + lat] = p[r] + b2v;
            }
        }
    }
}

// --- fp32 fallback (no workspace needed) for safety if ws_size is too small ---
__global__ __launch_bounds__(256) void fallback_kernel(const float* __restrict__ u, const float* __restrict__ W1,
                                                       const float* __restrict__ b1, const float* __restrict__ W2,
                                                       const float* __restrict__ b2, float* __restrict__ out) {
    int idx = blockIdx.x * 256 + threadIdx.x;
    if (idx >= BATCH * LATENT) return;
    int b = idx >> 7;
    int lat = idx & 127;
    const float* ub = u + b * INDIM;
    float s = 0.0f;
    for (int h = 0; h < HIDDEN; h++) {
        const float* wp = W1 + (lat * HIDDEN + h) * INDIM;
        float d = b1[lat * HIDDEN + h];
        for (int k = 0; k < INDIM; k++) d += ub[k] * wp[k];
        s += tanhf(d) * W2[lat * HIDDEN + h];
    }
    out[idx] = s + b2[lat];
}

extern "C" void kernel_launch(void* const* d_in, const int* in_sizes, int n_in,
                              void* d_out, int out_size, void* d_ws, size_t ws_size,
                              hipStream_t stream) {
    const float* u  = (const float*)d_in[0];
    const float* W1 = (const float*)d_in[1];
    const float* b1 = (const float*)d_in[2];
    const float* W2 = (const float*)d_in[3];
    const float* b2 = (const float*)d_in[4];
    float* out = (float*)d_out;

    const size_t UF_BYTES = (size_t)BATCH * KPAD * 2;          // 4 MiB
    const size_t WF_BYTES = (size_t)LATENT * HIDDEN * KPAD * 2; // 2 MiB

    if (ws_size < UF_BYTES + WF_BYTES) {
        fallback_kernel<<<(BATCH * LATENT + 255) / 256, 256, 0, stream>>>(u, W1, b1, W2, b2, out);
        return;
    }

    shortx8* uf = (shortx8*)d_ws;
    shortx8* wf = (shortx8*)((char*)d_ws + UF_BYTES);

    prep_u<<<(BATCH * KPAD / 8 + 255) / 256, 256, 0, stream>>>(u, uf);
    prep_w<<<(LATENT * HIDDEN * KPAD / 8 + 255) / 256, 256, 0, stream>>>(W1, b1, wf);
    branch_mlp<<<dim3(BATCH / 128, LATENT / 4), 256, 0, stream>>>(uf, wf, W2, b2, out);
}

// Round 3
// 121.333 us; speedup vs baseline: 1.3238x; 1.3238x over previous
//
#include <hip/hip_runtime.h>

#define BATCH 16384
#define LATENT 128
#define HIDDEN 64
#define INDIM 100
#define KPAD 128

typedef short shortx8 __attribute__((ext_vector_type(8)));
typedef float floatx4 __attribute__((ext_vector_type(4)));

__device__ __forceinline__ short f2bf(float f) {
    union { float f; unsigned u; } v; v.f = f;
    unsigned r = v.u + 0x7FFF + ((v.u >> 16) & 1);   // RNE, inputs finite
    return (short)(r >> 16);
}

#if __has_builtin(__builtin_amdgcn_exp2f)
#define EXP2F(x) __builtin_amdgcn_exp2f(x)
#else
#define EXP2F(x) __exp2f(x)
#endif
#if __has_builtin(__builtin_amdgcn_rcpf)
#define RCPF(x) __builtin_amdgcn_rcpf(x)
#else
#define RCPF(x) (1.0f / (x))
#endif

// Sum across each 16-lane DPP row, result in EVERY lane of the row.
// row_ror rotations (0x120+n) lose nothing at boundaries, so after
// ror:8,4,2,1 each lane has the full 16-lane sum regardless of the
// shift-direction convention (round-2 bug: row_shr sums land in lane 15).
#define DPP_REDUCE16(v) do {                                                              \
    v += __int_as_float(__builtin_amdgcn_update_dpp(0, __float_as_int(v), 0x128, 0xF, 0xF, true)); \
    v += __int_as_float(__builtin_amdgcn_update_dpp(0, __float_as_int(v), 0x124, 0xF, 0xF, true)); \
    v += __int_as_float(__builtin_amdgcn_update_dpp(0, __float_as_int(v), 0x122, 0xF, 0xF, true)); \
    v += __int_as_float(__builtin_amdgcn_update_dpp(0, __float_as_int(v), 0x121, 0xF, 0xF, true)); \
} while (0)

#define N_U_CHUNKS (BATCH * KPAD / 8)            // 262144
#define N_W_CHUNKS (LATENT * HIDDEN * KPAD / 8)  // 131072

// --- fused pre-pass: build bf16 fragment-major uf (b1 folded via ones col k=100)
// and wf (B^T layout, b1 at k=100) in one launch ---
__global__ __launch_bounds__(256) void prep_all(const float* __restrict__ u,
                                                const float* __restrict__ W1,
                                                const float* __restrict__ b1,
                                                shortx8* __restrict__ uf,
                                                shortx8* __restrict__ wf) {
    int c = blockIdx.x * 256 + threadIdx.x;
    if (c < N_U_CHUNKS) {
        int lane = c & 63;
        int kt = (c >> 6) & 3;
        int g = c >> 8;
        int row = g * 16 + (lane & 15);
        int kbase = kt * 32 + ((lane >> 4) << 3);
        shortx8 v;
        if (kbase + 7 < INDIM) {
            const float4* p = (const float4*)(u + row * INDIM + kbase);
            float4 f0 = p[0], f1 = p[1];
            v[0] = f2bf(f0.x); v[1] = f2bf(f0.y); v[2] = f2bf(f0.z); v[3] = f2bf(f0.w);
            v[4] = f2bf(f1.x); v[5] = f2bf(f1.y); v[6] = f2bf(f1.z); v[7] = f2bf(f1.w);
        } else {
#pragma unroll
            for (int j = 0; j < 8; j++) {
                int k = kbase + j;
                float f = (k < INDIM) ? u[row * INDIM + k] : (k == INDIM ? 1.0f : 0.0f);
                v[j] = f2bf(f);
            }
        }
        uf[c] = v;
    } else {
        int c2 = c - N_U_CHUNKS;
        int lane = c2 & 63;
        int kt = (c2 >> 6) & 3;
        int nt = (c2 >> 8) & 3;
        int lat = c2 >> 10;
        int h = nt * 16 + (lane & 15);
        int hw = lat * HIDDEN + h;
        int kbase = kt * 32 + ((lane >> 4) << 3);
        shortx8 v;
        if (kbase + 7 < INDIM) {
            const float4* p = (const float4*)(W1 + hw * INDIM + kbase);
            float4 f0 = p[0], f1 = p[1];
            v[0] = f2bf(f0.x); v[1] = f2bf(f0.y); v[2] = f2bf(f0.z); v[3] = f2bf(f0.w);
            v[4] = f2bf(f1.x); v[5] = f2bf(f1.y); v[6] = f2bf(f1.z); v[7] = f2bf(f1.w);
        } else {
#pragma unroll
            for (int j = 0; j < 8; j++) {
                int k = kbase + j;
                float f = (k < INDIM) ? W1[hw * INDIM + k] : (k == INDIM ? b1[hw] : 0.0f);
                v[j] = f2bf(f);
            }
        }
        wf[c2] = v;
    }
}

// --- main fused kernel ---
// grid (128, 32): bx = 128-row batch block, by = 4-latent quad. 256 thr = 4 waves.
// wave w: row-groups g0=bx*8+w*2, g0+1 (16 rows each). All 4 latents of the quad.
// launch_bounds (256,2): 256-VGPR cap -> no AGPR spill traffic (round-1 had VGPR=64 + spills).
__global__ __launch_bounds__(256, 2) void branch_mlp(const shortx8* __restrict__ uf,
                                                     const shortx8* __restrict__ wf,
                                                     const float* __restrict__ W2,
                                                     const float* __restrict__ b2,
                                                     float* __restrict__ out) {
    int tid = threadIdx.x;
    int lane = tid & 63;
    int w = tid >> 6;
    int bx = blockIdx.x;
    int by = blockIdx.y;
    int g0 = bx * 8 + w * 2;
    int q = lane >> 4;
    int col = lane & 15;

    // A fragments for this wave's 32 rows, all K (reused across 4 latents)
    shortx8 a[2][4];
#pragma unroll
    for (int gi = 0; gi < 2; gi++)
#pragma unroll
        for (int kt = 0; kt < 4; kt++)
            a[gi][kt] = uf[((g0 + gi) * 4 + kt) * 64 + lane];

#pragma unroll
    for (int li = 0; li < 4; li++) {
        int lat = by * 4 + li;
        const shortx8* wfl = wf + (size_t)lat * 16 * 64;

        // prefetch epilogue operands before the MFMA block
        float w2v[4];
#pragma unroll
        for (int nt = 0; nt < 4; nt++) w2v[nt] = W2[lat * HIDDEN + nt * 16 + col];
        float b2v = b2[lat];

        floatx4 acc[2][4] = {};
#pragma unroll
        for (int kt = 0; kt < 4; kt++) {
#pragma unroll
            for (int nt = 0; nt < 4; nt++) {
                shortx8 bf = wfl[(nt * 4 + kt) * 64 + lane];
#pragma unroll
                for (int gi = 0; gi < 2; gi++)
                    acc[gi][nt] = __builtin_amdgcn_mfma_f32_16x16x32_bf16(a[gi][kt], bf, acc[gi][nt], 0, 0, 0);
            }
        }

        // epilogue: t = 1 - 2/(exp2(2log2e*x)+1); s += t*W2; DPP-rotate-reduce over 16 cols
#pragma unroll
        for (int gi = 0; gi < 2; gi++) {
            float p[4];
#pragma unroll
            for (int r = 0; r < 4; r++) {
                float s = 0.0f;
#pragma unroll
                for (int nt = 0; nt < 4; nt++) {
                    float x = acc[gi][nt][r];
                    float e = EXP2F(x * 2.88539008177793f);   // exp(2x)
                    float rr = RCPF(e + 1.0f);
                    float t = fmaf(-2.0f, rr, 1.0f);           // tanh(x)
                    s = fmaf(t, w2v[nt], s);
                }
                p[r] = s;
            }
#pragma unroll
            for (int r = 0; r < 4; r++) DPP_REDUCE16(p[r]);
            if (col == 0) {
                int rowbase = (g0 + gi) * 16 + q * 4;
#pragma unroll
                for (int r = 0; r < 4; r++)
                    out[(rowbase + r) * LATENT + lat] = p[r] + b2v;
            }
        }
    }
}

// --- fp32 fallback (no workspace needed) ---
__global__ __launch_bounds__(256) void fallback_kernel(const float* __restrict__ u, const float* __restrict__ W1,
                                                       const float* __restrict__ b1, const float* __restrict__ W2,
                                                       const float* __restrict__ b2, float* __restrict__ out) {
    int idx = blockIdx.x * 256 + threadIdx.x;
    if (idx >= BATCH * LATENT) return;
    int b = idx >> 7;
    int lat = idx & 127;
    const float* ub = u + b * INDIM;
    float s = 0.0f;
    for (int h = 0; h < HIDDEN; h++) {
        const float* wp = W1 + (lat * HIDDEN + h) * INDIM;
        float d = b1[lat * HIDDEN + h];
        for (int k = 0; k < INDIM; k++) d += ub[k] * wp[k];
        s += tanhf(d) * W2[lat * HIDDEN + h];
    }
    out[idx] = s + b2[lat];
}

extern "C" void kernel_launch(void* const* d_in, const int* in_sizes, int n_in,
                              void* d_out, int out_size, void* d_ws, size_t ws_size,
                              hipStream_t stream) {
    const float* u  = (const float*)d_in[0];
    const float* W1 = (const float*)d_in[1];
    const float* b1 = (const float*)d_in[2];
    const float* W2 = (const float*)d_in[3];
    const float* b2 = (const float*)d_in[4];
    float* out = (float*)d_out;

    const size_t UF_BYTES = (size_t)BATCH * KPAD * 2;           // 4 MiB
    const size_t WF_BYTES = (size_t)LATENT * HIDDEN * KPAD * 2; // 2 MiB

    if (ws_size < UF_BYTES + WF_BYTES) {
        fallback_kernel<<<(BATCH * LATENT + 255) / 256, 256, 0, stream>>>(u, W1, b1, W2, b2, out);
        return;
    }

    shortx8* uf = (shortx8*)d_ws;
    shortx8* wf = (shortx8*)((char*)d_ws + UF_BYTES);

    prep_all<<<(N_U_CHUNKS + N_W_CHUNKS) / 256, 256, 0, stream>>>(u, W1, b1, uf, wf);
    branch_mlp<<<dim3(BATCH / 128, LATENT / 4), 256, 0, stream>>>(uf, wf, W2, b2, out);
}